// Round 3
// baseline (512.918 us; speedup 1.0000x reference)
//
#include <hip/hip_runtime.h>
#include <math.h>

// Problem constants
#define NB 8
#define SEQ 1024
#define DM 1536
#define NHEAD 12
#define DHEAD 128
#define MAXC 256
#define QKVN 4608
#define THRESH 0.85f

typedef unsigned short u16;
typedef __attribute__((ext_vector_type(8))) __bf16 bf16x8;
typedef __attribute__((ext_vector_type(4))) float f32x4;

struct __align__(4) U2 { u16 x, y; };
struct __align__(8) U4 { u16 x, y, z, w; };

__device__ __forceinline__ float bf2f(u16 u) {
  union { unsigned i; float f; } c; c.i = ((unsigned)u) << 16; return c.f;
}
__device__ __forceinline__ u16 f2bf(float f) {
  union { float f; unsigned i; } c; c.f = f;
  unsigned r = c.i + 0x7FFFu + ((c.i >> 16) & 1u);  // RNE
  return (u16)(r >> 16);
}

// ---------------------------------------------------------------- converts
// One launch, 5 arrays (grid-stride each range).
__global__ __launch_bounds__(256) void cvt5_bf16_kernel(
    const float* __restrict__ i0, u16* __restrict__ o0, int n0,
    const float* __restrict__ i1, u16* __restrict__ o1, int n1,
    const float* __restrict__ i2, u16* __restrict__ o2, int n2,
    const float* __restrict__ i3, u16* __restrict__ o3, int n3,
    const float* __restrict__ i4, u16* __restrict__ o4, int n4) {
  const int stride = gridDim.x * blockDim.x;
  const int t0 = blockIdx.x * blockDim.x + threadIdx.x;
  const float* ins[5] = {i0, i1, i2, i3, i4};
  u16* outs[5] = {o0, o1, o2, o3, o4};
  const int ns[5] = {n0, n1, n2, n3, n4};
#pragma unroll
  for (int a = 0; a < 5; ++a) {
    const float* in = ins[a];
    u16* out = outs[a];
    for (int i = t0; i < ns[a]; i += stride) {
      float4 f = ((const float4*)in)[i];
      U4 u; u.x = f2bf(f.x); u.y = f2bf(f.y); u.z = f2bf(f.z); u.w = f2bf(f.w);
      ((U4*)out)[i] = u;
    }
  }
}

// ------------------------------------------------------------- segmentation
// One wave per batch. Ballot-scan of boundaries>0.85 -> chunk starts/lens.
__global__ __launch_bounds__(64) void segment_kernel(
    const float* __restrict__ bnd, int* __restrict__ nchunks,
    int* __restrict__ starts, int* __restrict__ lens) {
  const int b = blockIdx.x;
  const int lane = threadIdx.x;
  int running = 0;
  for (int g = 0; g < SEQ / 64; ++g) {
    int s = g * 64 + lane;
    bool isb = bnd[b * SEQ + s] > THRESH;
    unsigned long long mask = __ballot(isb ? 1 : 0);
    int excl = __popcll(mask & ((1ULL << lane) - 1ULL));
    if (isb) {
      int c = running + excl;
      if (c <= MAXC) starts[b * (MAXC + 1) + c] = s;
    }
    running += __popcll(mask);
  }
  if (lane == 0) nchunks[b] = running;
  __syncthreads();  // drain stores before re-reading starts
  int ncl = min(running, MAXC);
  for (int c = lane; c < MAXC; c += 64) {
    int v = 0;
    if (c < ncl) {
      int st = starts[b * (MAXC + 1) + c];
      int en = (c + 1 < running) ? starts[b * (MAXC + 1) + c + 1] : SEQ;
      v = en - st;
    }
    lens[b * MAXC + c] = v;
  }
}

// -------------------------------------------------------------------- GEMM
// C[M,N] = A[M,K] @ B[N,K]^T, bf16 inputs, f32 accumulate.
// 128x128 tile, BK=32, 4 waves, each wave owns a 64x64 quadrant (4x4 frags).
// LDS layout per 16-row group: [kgroup(4)][row(16)][8 elems] so that the
// MFMA fragment ds_read is lane-linear (byte = lane*16) -> conflict-free.
// global_load_lds writes linearly (base + lane*16B); the per-lane GLOBAL
// source is permuted to match (rule: swizzle source + read identically).
// MODE 1: out_bf16 = acc + bias                          (QKV)
// MODE 2: chunks epilogue (zero-if-empty, +out_b +size_emb +pos_enc) -> bf16
// MODE 3: out_bf16 = gelu(acc + bias)                    (MLP fc1)
// MODE 4: out_f32  = acc + bias                          (MLP fc2)
template <int MODE>
__global__ __launch_bounds__(256) void gemm_bf16_kernel(
    const u16* __restrict__ A, const u16* __restrict__ B,
    const int M, const int N, const int K,
    const float* __restrict__ bias,
    u16* __restrict__ outB, float* __restrict__ outF,
    const int* __restrict__ lens, const float* __restrict__ semb,
    const float* __restrict__ pos) {
  __shared__ __align__(16) u16 As[128 * 32];
  __shared__ __align__(16) u16 Bs[128 * 32];
  const int tid = threadIdx.x;
  const int wave = tid >> 6;
  const int lane = tid & 63;
  const int row0 = blockIdx.y * 128;
  const int col0 = blockIdx.x * 128;
  const int wm = (wave >> 1) * 64;
  const int wn = (wave & 1) * 64;
  const int sr = lane & 15;        // staging row within 16-row group
  const int sc = (lane >> 4) * 8;  // staging k offset (8 bf16 = 16B)
  const int rr = lane & 15;
  f32x4 acc[4][4] = {};

  for (int k0 = 0; k0 < K; k0 += 32) {
    __syncthreads();  // previous iteration's LDS reads complete
#pragma unroll
    for (int t = 0; t < 2; ++t) {
      const int li = wave * 2 + t;  // 16-row group id, 0..7
      u16* ga = const_cast<u16*>(A) + (size_t)(row0 + li * 16 + sr) * K + (k0 + sc);
      u16* gb = const_cast<u16*>(B) + (size_t)(col0 + li * 16 + sr) * K + (k0 + sc);
      __builtin_amdgcn_global_load_lds(
          (__attribute__((address_space(1))) void*)ga,
          (__attribute__((address_space(3))) void*)(As + li * 512), 16, 0, 0);
      __builtin_amdgcn_global_load_lds(
          (__attribute__((address_space(1))) void*)gb,
          (__attribute__((address_space(3))) void*)(Bs + li * 512), 16, 0, 0);
    }
    __syncthreads();  // drains vmcnt -> staging visible
    bf16x8 af[4], bfr[4];
#pragma unroll
    for (int m = 0; m < 4; ++m)
      af[m] = *(const bf16x8*)(As + ((wm >> 4) + m) * 512 + lane * 8);
#pragma unroll
    for (int n = 0; n < 4; ++n)
      bfr[n] = *(const bf16x8*)(Bs + ((wn >> 4) + n) * 512 + lane * 8);
#pragma unroll
    for (int m = 0; m < 4; ++m)
#pragma unroll
      for (int n = 0; n < 4; ++n)
        acc[m][n] = __builtin_amdgcn_mfma_f32_16x16x32_bf16(af[m], bfr[n], acc[m][n], 0, 0, 0);
  }

  // epilogue: C/D layout col = lane&15, row = (lane>>4)*4 + reg
  const int rg = (lane >> 4) * 4;
#pragma unroll
  for (int m = 0; m < 4; ++m) {
#pragma unroll
    for (int n = 0; n < 4; ++n) {
      const int col = col0 + wn + n * 16 + rr;
#pragma unroll
      for (int j = 0; j < 4; ++j) {
        const int row = row0 + wm + m * 16 + rg + j;
        float v = acc[m][n][j];
        if (MODE == 1) {
          outB[(size_t)row * N + col] = f2bf(v + bias[col]);
        } else if (MODE == 2) {
          const int len = lens[row];
          float val = 0.f;
          if (len > 0) {
            const int si = len < 1023 ? len : 1023;
            val = v + bias[col] + semb[(size_t)si * DM + col];
          }
          val += pos[(size_t)(row & (MAXC - 1)) * DM + col];
          outB[(size_t)row * N + col] = f2bf(val);
        } else if (MODE == 3) {
          float z = v + bias[col];
          float gel = 0.5f * z * (1.f + erff(z * 0.70710678118654752440f));
          outB[(size_t)row * N + col] = f2bf(gel);
        } else {
          outF[(size_t)row * N + col] = v + bias[col];
        }
      }
    }
  }
}

// -------------------------------------------------------- chunk attention v2
// One wave per (head, chunk, batch). Pooled ctx only:
//   pooled[d] = (1/L) * sum_j g_j * v_j[d],  g_j = sum_i p_ij
// Scores via MFMA 16x16x32; Q/K fragments loaded directly from global.
__global__ __launch_bounds__(64) void chunk_attn_kernel(
    const u16* __restrict__ qkv, const int* __restrict__ nchunks,
    const int* __restrict__ starts, const int* __restrict__ lens,
    u16* __restrict__ pooled) {
  __shared__ float g_lds[SEQ];
  const int h = blockIdx.x;
  const int c = blockIdx.y;
  const int b = blockIdx.z;
  const int lane = threadIdx.x;
  const int nc = min(nchunks[b], MAXC);
  u16* prow = pooled + ((size_t)(b * MAXC + c)) * DM + h * DHEAD;
  if (c >= nc) {  // empty chunk: pooled ctx = 0
    U2 z; z.x = 0; z.y = 0;
    *(U2*)(prow + lane * 2) = z;
    return;
  }
  const int s0 = starts[b * (MAXC + 1) + c];
  const int L = lens[b * MAXC + c];
  const u16* Qb = qkv + ((size_t)(b * SEQ + s0)) * QKVN + h * DHEAD;
  const u16* Kb = Qb + DM;
  const u16* Vb = Qb + 2 * DM;

  for (int j = lane; j < L; j += 64) g_lds[j] = 0.f;
  __syncthreads();

  const int col = lane & 15;   // fragment row/col index
  const int grp = lane >> 4;   // k-subgroup / row group
  const float scale = 0.08838834764831845f;  // 1/sqrt(128)
  const int NT = (L + 15) >> 4;

  for (int qt = 0; qt < NT; ++qt) {
    const int qr = qt * 16 + col;
    const int qrc = qr < L ? qr : (L - 1);  // clamp (masked later)
    bf16x8 qf[4];
#pragma unroll
    for (int s = 0; s < 4; ++s)
      qf[s] = *(const bf16x8*)(Qb + (size_t)qrc * QKVN + s * 32 + grp * 8);

    float m[4] = {-3e38f, -3e38f, -3e38f, -3e38f};
    float den[4] = {0.f, 0.f, 0.f, 0.f};
    f32x4 sc_last = {0.f, 0.f, 0.f, 0.f};

    // ---- pass 1: per-query-row online max + denom over key tiles
    for (int kt = 0; kt < NT; ++kt) {
      const int kr = kt * 16 + col;
      const bool kvalid = kr < L;
      const int krc = kvalid ? kr : (L - 1);
      f32x4 sc = {0.f, 0.f, 0.f, 0.f};
#pragma unroll
      for (int s = 0; s < 4; ++s) {
        bf16x8 kf = *(const bf16x8*)(Kb + (size_t)krc * QKVN + s * 32 + grp * 8);
        sc = __builtin_amdgcn_mfma_f32_16x16x32_bf16(qf[s], kf, sc, 0, 0, 0);
      }
      sc_last = sc;
#pragma unroll
      for (int j = 0; j < 4; ++j) {
        float sj = sc[j] * scale;
        float mv = kvalid ? sj : -3e38f;
        mv = fmaxf(mv, __shfl_xor(mv, 1));
        mv = fmaxf(mv, __shfl_xor(mv, 2));
        mv = fmaxf(mv, __shfl_xor(mv, 4));
        mv = fmaxf(mv, __shfl_xor(mv, 8));
        float mn = fmaxf(m[j], mv);
        float pv = kvalid ? __expf(sj - mn) : 0.f;
        pv += __shfl_xor(pv, 1);
        pv += __shfl_xor(pv, 2);
        pv += __shfl_xor(pv, 4);
        pv += __shfl_xor(pv, 8);
        den[j] = den[j] * __expf(m[j] - mn) + pv;
        m[j] = mn;
      }
    }
    float inv[4];
#pragma unroll
    for (int j = 0; j < 4; ++j) {
      const bool rv = (qt * 16 + grp * 4 + j) < L;
      inv[j] = rv ? 1.f / den[j] : 0.f;   // invalid rows contribute 0
    }
    // ---- pass 2: g_j += sum_rows p; NT==1 reuses pass-1 scores
    for (int kt = 0; kt < NT; ++kt) {
      const int kr = kt * 16 + col;
      const bool kvalid = kr < L;
      f32x4 sc;
      if (NT == 1) {
        sc = sc_last;
      } else {
        const int krc = kvalid ? kr : (L - 1);
        f32x4 z = {0.f, 0.f, 0.f, 0.f};
        sc = z;
#pragma unroll
        for (int s = 0; s < 4; ++s) {
          bf16x8 kf = *(const bf16x8*)(Kb + (size_t)krc * QKVN + s * 32 + grp * 8);
          sc = __builtin_amdgcn_mfma_f32_16x16x32_bf16(qf[s], kf, sc, 0, 0, 0);
        }
      }
      float colsum = 0.f;
#pragma unroll
      for (int j = 0; j < 4; ++j)
        colsum += __expf(sc[j] * scale - m[j]) * inv[j];
      colsum += __shfl_xor(colsum, 16);
      colsum += __shfl_xor(colsum, 32);
      if (grp == 0 && kvalid) g_lds[kt * 16 + col] += colsum;
    }
  }
  __syncthreads();

  // pooled = (1/L) * sum_j g_j * v_j   (lanes over dims, coalesced V)
  float a0 = 0.f, a1 = 0.f;
  for (int j = 0; j < L; ++j) {
    float gj = g_lds[j];
    U2 vv = *(const U2*)(Vb + (size_t)j * QKVN + lane * 2);
    a0 += gj * bf2f(vv.x);
    a1 += gj * bf2f(vv.y);
  }
  const float invL = 1.f / (float)L;
  U2 r; r.x = f2bf(a0 * invL); r.y = f2bf(a1 * invL);
  *(U2*)(prow + lane * 2) = r;
}

// ---------------------------------------------------------------- LayerNorm
__global__ __launch_bounds__(256) void ln_kernel(
    const float* __restrict__ h2, const float* __restrict__ gamma,
    const float* __restrict__ beta, float* __restrict__ out) {
  const int row = blockIdx.x;
  const float* x = h2 + (size_t)row * DM;
  float* o = out + (size_t)row * DM;
  const int tid = threadIdx.x;
  float v[6];
  float s = 0.f;
#pragma unroll
  for (int i = 0; i < 6; ++i) { v[i] = x[tid + i * 256]; s += v[i]; }
  __shared__ float red[8];
#pragma unroll
  for (int off = 32; off; off >>= 1) s += __shfl_xor(s, off);
  if ((tid & 63) == 0) red[tid >> 6] = s;
  __syncthreads();
  const float mu = (red[0] + red[1] + red[2] + red[3]) * (1.f / (float)DM);
  float vs = 0.f;
#pragma unroll
  for (int i = 0; i < 6; ++i) { float d = v[i] - mu; vs += d * d; }
#pragma unroll
  for (int off = 32; off; off >>= 1) vs += __shfl_xor(vs, off);
  __shared__ float red2[8];
  if ((tid & 63) == 0) red2[tid >> 6] = vs;
  __syncthreads();
  const float var = (red2[0] + red2[1] + red2[2] + red2[3]) * (1.f / (float)DM);
  const float inv = rsqrtf(var + 1e-5f);
#pragma unroll
  for (int i = 0; i < 6; ++i) {
    const int cidx = tid + i * 256;
    o[cidx] = (v[i] - mu) * inv * gamma[cidx] + beta[cidx];
  }
}

// ------------------------------------------------------------------ launch
extern "C" void kernel_launch(void* const* d_in, const int* in_sizes, int n_in,
                              void* d_out, int out_size, void* d_ws, size_t ws_size,
                              hipStream_t stream) {
  const float* x    = (const float*)d_in[0];
  const float* bnd  = (const float*)d_in[1];
  const float* wqkv = (const float*)d_in[2];
  const float* bqkv = (const float*)d_in[3];
  const float* wout = (const float*)d_in[4];
  const float* bout = (const float*)d_in[5];
  const float* w1   = (const float*)d_in[6];
  const float* b1   = (const float*)d_in[7];
  const float* w2   = (const float*)d_in[8];
  const float* b2   = (const float*)d_in[9];
  const float* lng  = (const float*)d_in[10];
  const float* lnb  = (const float*)d_in[11];
  const float* pos  = (const float*)d_in[12];
  const float* semb = (const float*)d_in[13];
  float* out = (float*)d_out;

  // workspace layout (~169 MiB)
  char* ws = (char*)d_ws;
  size_t off = 0;
  auto alloc = [&](size_t bytes) -> char* {
    char* p = ws + off;
    off += (bytes + 255) & ~(size_t)255;
    return p;
  };
  u16* x_bf    = (u16*)alloc((size_t)NB * SEQ * DM * 2);        // 25.2 MB
  u16* wqkv_bf = (u16*)alloc((size_t)3 * DM * DM * 2);          // 14.2 MB
  u16* wout_bf = (u16*)alloc((size_t)DM * DM * 2);              //  4.7 MB
  u16* w1_bf   = (u16*)alloc((size_t)2 * DM * DM * 2);          //  9.4 MB
  u16* w2_bf   = (u16*)alloc((size_t)2 * DM * DM * 2);          //  9.4 MB
  u16* qkv_bf  = (u16*)alloc((size_t)NB * SEQ * QKVN * 2);      // 75.5 MB
  int* nchunks = (int*)alloc(NB * 4);
  int* starts  = (int*)alloc(NB * (MAXC + 1) * 4);
  int* lens    = (int*)alloc(NB * MAXC * 4);
  u16* pooled  = (u16*)alloc((size_t)NB * MAXC * DM * 2);       //  6.3 MB
  u16* chunks  = (u16*)alloc((size_t)NB * MAXC * DM * 2);       //  6.3 MB
  u16* h1      = (u16*)alloc((size_t)NB * MAXC * 2 * DM * 2);   // 12.6 MB
  float* h2    = (float*)alloc((size_t)NB * MAXC * DM * 4);     // 12.6 MB
  (void)ws_size; (void)in_sizes; (void)n_in; (void)out_size;

  // f32 -> bf16 converts (single launch)
  cvt5_bf16_kernel<<<2048, 256, 0, stream>>>(
      x, x_bf, NB * SEQ * DM / 4,
      wqkv, wqkv_bf, 3 * DM * DM / 4,
      wout, wout_bf, DM * DM / 4,
      w1, w1_bf, 2 * DM * DM / 4,
      w2, w2_bf, 2 * DM * DM / 4);

  // segmentation
  segment_kernel<<<NB, 64, 0, stream>>>(bnd, nchunks, starts, lens);

  // QKV projection: [8192,1536] @ [4608,1536]^T -> bf16 [8192,4608]
  gemm_bf16_kernel<1><<<dim3(QKVN / 128, NB * SEQ / 128), 256, 0, stream>>>(
      x_bf, wqkv_bf, NB * SEQ, QKVN, DM, bqkv, qkv_bf, nullptr, nullptr, nullptr, nullptr);

  // per-chunk attention -> pooled ctx (bf16 [2048,1536])
  chunk_attn_kernel<<<dim3(NHEAD, MAXC, NB), 64, 0, stream>>>(
      qkv_bf, nchunks, starts, lens, pooled);

  // out-proj + chunk assembly: [2048,1536] @ [1536,1536]^T -> chunks bf16
  gemm_bf16_kernel<2><<<dim3(DM / 128, NB * MAXC / 128), 256, 0, stream>>>(
      pooled, wout_bf, NB * MAXC, DM, DM, bout, chunks, nullptr, lens, semb, pos);

  // MLP fc1 + GELU: [2048,1536] @ [3072,1536]^T -> h1 bf16
  gemm_bf16_kernel<3><<<dim3(2 * DM / 128, NB * MAXC / 128), 256, 0, stream>>>(
      chunks, w1_bf, NB * MAXC, 2 * DM, DM, b1, h1, nullptr, nullptr, nullptr, nullptr);

  // MLP fc2: [2048,3072] @ [1536,3072]^T -> h2 f32
  gemm_bf16_kernel<4><<<dim3(DM / 128, NB * MAXC / 128), 256, 0, stream>>>(
      h1, w2_bf, NB * MAXC, DM, 2 * DM, b2, nullptr, h2, nullptr, nullptr, nullptr);

  // LayerNorm -> d_out
  ln_kernel<<<NB * MAXC, 256, 0, stream>>>(h2, lng, lnb, out);
}

// Round 4
// 406.879 us; speedup vs baseline: 1.2606x; 1.2606x over previous
//
#include <hip/hip_runtime.h>
#include <math.h>

// Problem constants
#define NB 8
#define SEQ 1024
#define DM 1536
#define NHEAD 12
#define DHEAD 128
#define MAXC 256
#define QKVN 4608
#define THRESH 0.85f

typedef unsigned short u16;
typedef __attribute__((ext_vector_type(8))) __bf16 bf16x8;
typedef __attribute__((ext_vector_type(4))) float f32x4;

struct __align__(4) U2 { u16 x, y; };
struct __align__(8) U4 { u16 x, y, z, w; };

__device__ __forceinline__ float bf2f(u16 u) {
  union { unsigned i; float f; } c; c.i = ((unsigned)u) << 16; return c.f;
}
__device__ __forceinline__ u16 f2bf(float f) {
  union { float f; unsigned i; } c; c.f = f;
  unsigned r = c.i + 0x7FFFu + ((c.i >> 16) & 1u);  // RNE
  return (u16)(r >> 16);
}

// ---------------------------------------------------------------- converts
// One launch, 5 arrays (grid-stride each range).
__global__ __launch_bounds__(256) void cvt5_bf16_kernel(
    const float* __restrict__ i0, u16* __restrict__ o0, int n0,
    const float* __restrict__ i1, u16* __restrict__ o1, int n1,
    const float* __restrict__ i2, u16* __restrict__ o2, int n2,
    const float* __restrict__ i3, u16* __restrict__ o3, int n3,
    const float* __restrict__ i4, u16* __restrict__ o4, int n4) {
  const int stride = gridDim.x * blockDim.x;
  const int t0 = blockIdx.x * blockDim.x + threadIdx.x;
  const float* ins[5] = {i0, i1, i2, i3, i4};
  u16* outs[5] = {o0, o1, o2, o3, o4};
  const int ns[5] = {n0, n1, n2, n3, n4};
#pragma unroll
  for (int a = 0; a < 5; ++a) {
    const float* in = ins[a];
    u16* out = outs[a];
    for (int i = t0; i < ns[a]; i += stride) {
      float4 f = ((const float4*)in)[i];
      U4 u; u.x = f2bf(f.x); u.y = f2bf(f.y); u.z = f2bf(f.z); u.w = f2bf(f.w);
      ((U4*)out)[i] = u;
    }
  }
}

// ------------------------------------------------------------- segmentation
// One wave per batch. Ballot-scan of boundaries>0.85 -> chunk starts/lens.
__global__ __launch_bounds__(64) void segment_kernel(
    const float* __restrict__ bnd, int* __restrict__ nchunks,
    int* __restrict__ starts, int* __restrict__ lens) {
  const int b = blockIdx.x;
  const int lane = threadIdx.x;
  int running = 0;
  for (int g = 0; g < SEQ / 64; ++g) {
    int s = g * 64 + lane;
    bool isb = bnd[b * SEQ + s] > THRESH;
    unsigned long long mask = __ballot(isb ? 1 : 0);
    int excl = __popcll(mask & ((1ULL << lane) - 1ULL));
    if (isb) {
      int c = running + excl;
      if (c <= MAXC) starts[b * (MAXC + 1) + c] = s;
    }
    running += __popcll(mask);
  }
  if (lane == 0) nchunks[b] = running;
  __syncthreads();  // drain stores before re-reading starts
  int ncl = min(running, MAXC);
  for (int c = lane; c < MAXC; c += 64) {
    int v = 0;
    if (c < ncl) {
      int st = starts[b * (MAXC + 1) + c];
      int en = (c + 1 < running) ? starts[b * (MAXC + 1) + c + 1] : SEQ;
      v = en - st;
    }
    lens[b * MAXC + c] = v;
  }
}

// -------------------------------------------------------------------- GEMM
// C[M,N] = A[M,K] @ B[N,K]^T, bf16 inputs, f32 accumulate.
// 128x128 tile, BK=32, 4 waves, each wave owns a 64x64 quadrant (4x4 frags).
// LDS: per 16-row group, 64 chunks of 16B (chunk c = row(c>>2), k8(c&3)).
// Slot permutation sigma(c) = c ^ ((c>>3)&7) (involution, bits 0-2 only):
//   - staging: lane l (slot l, linear per global_load_lds) fetches global
//     chunk g = sigma(l); sigma moves chunks only within 128B (2-row) spans
//     -> per-16-lane-phase global addresses hit the same 64B lines as the
//     identity mapping => coalescing preserved.
//   - fragment read: chunk c=(lane&15)*4+(lane>>4) read at slot sigma(c);
//     per 16-lane phase, sigma(c) mod 8 covers all 8 bank-groups exactly
//     twice => 2 lanes/bank = conflict-free (m136).
// MODE 1: out_bf16 = acc + bias                          (QKV)
// MODE 2: chunks epilogue (zero-if-empty, +out_b +size_emb +pos_enc) -> bf16
// MODE 3: out_bf16 = gelu(acc + bias)                    (MLP fc1)
// MODE 4: out_f32  = acc + bias                          (MLP fc2)
template <int MODE>
__global__ __launch_bounds__(256) void gemm_bf16_kernel(
    const u16* __restrict__ A, const u16* __restrict__ B,
    const int M, const int N, const int K,
    const float* __restrict__ bias,
    u16* __restrict__ outB, float* __restrict__ outF,
    const int* __restrict__ lens, const float* __restrict__ semb,
    const float* __restrict__ pos) {
  __shared__ __align__(16) u16 As[128 * 32];
  __shared__ __align__(16) u16 Bs[128 * 32];
  const int tid = threadIdx.x;
  const int wave = tid >> 6;
  const int lane = tid & 63;
  const int row0 = blockIdx.y * 128;
  const int col0 = blockIdx.x * 128;
  const int wm = (wave >> 1) * 64;
  const int wn = (wave & 1) * 64;
  // staging source permutation: lane's slot holds global chunk g
  const int gch = lane ^ ((lane >> 3) & 7);
  const int sr = gch >> 2;         // staging row within 16-row group
  const int sc = (gch & 3) * 8;    // staging k offset (8 bf16 = 16B)
  // fragment-read slot: chunk c -> slot sigma(c)
  const int rr = lane & 15;
  const int kg = lane >> 4;
  const int cwant = rr * 4 + kg;
  const int slot = cwant ^ ((cwant >> 3) & 7);
  f32x4 acc[4][4] = {};

  for (int k0 = 0; k0 < K; k0 += 32) {
    __syncthreads();  // previous iteration's LDS reads complete
#pragma unroll
    for (int t = 0; t < 2; ++t) {
      const int li = wave * 2 + t;  // 16-row group id, 0..7
      u16* ga = const_cast<u16*>(A) + (size_t)(row0 + li * 16 + sr) * K + (k0 + sc);
      u16* gb = const_cast<u16*>(B) + (size_t)(col0 + li * 16 + sr) * K + (k0 + sc);
      __builtin_amdgcn_global_load_lds(
          (__attribute__((address_space(1))) void*)ga,
          (__attribute__((address_space(3))) void*)(As + li * 512), 16, 0, 0);
      __builtin_amdgcn_global_load_lds(
          (__attribute__((address_space(1))) void*)gb,
          (__attribute__((address_space(3))) void*)(Bs + li * 512), 16, 0, 0);
    }
    __syncthreads();  // drains vmcnt -> staging visible
    bf16x8 af[4], bfr[4];
#pragma unroll
    for (int m = 0; m < 4; ++m)
      af[m] = *(const bf16x8*)(As + ((wm >> 4) + m) * 512 + slot * 8);
#pragma unroll
    for (int n = 0; n < 4; ++n)
      bfr[n] = *(const bf16x8*)(Bs + ((wn >> 4) + n) * 512 + slot * 8);
#pragma unroll
    for (int m = 0; m < 4; ++m)
#pragma unroll
      for (int n = 0; n < 4; ++n)
        acc[m][n] = __builtin_amdgcn_mfma_f32_16x16x32_bf16(af[m], bfr[n], acc[m][n], 0, 0, 0);
  }

  // epilogue: C/D layout col = lane&15, row = (lane>>4)*4 + reg
  const int rg = (lane >> 4) * 4;
#pragma unroll
  for (int m = 0; m < 4; ++m) {
#pragma unroll
    for (int n = 0; n < 4; ++n) {
      const int col = col0 + wn + n * 16 + rr;
#pragma unroll
      for (int j = 0; j < 4; ++j) {
        const int row = row0 + wm + m * 16 + rg + j;
        float v = acc[m][n][j];
        if (MODE == 1) {
          outB[(size_t)row * N + col] = f2bf(v + bias[col]);
        } else if (MODE == 2) {
          const int len = lens[row];
          float val = 0.f;
          if (len > 0) {
            const int si = len < 1023 ? len : 1023;
            val = v + bias[col] + semb[(size_t)si * DM + col];
          }
          val += pos[(size_t)(row & (MAXC - 1)) * DM + col];
          outB[(size_t)row * N + col] = f2bf(val);
        } else if (MODE == 3) {
          float z = v + bias[col];
          float gel = 0.5f * z * (1.f + erff(z * 0.70710678118654752440f));
          outB[(size_t)row * N + col] = f2bf(gel);
        } else {
          outF[(size_t)row * N + col] = v + bias[col];
        }
      }
    }
  }
}

// -------------------------------------------------------- chunk attention v2
// One wave per (head, chunk, batch). Pooled ctx only:
//   pooled[d] = (1/L) * sum_j g_j * v_j[d],  g_j = sum_i p_ij
// Scores via MFMA 16x16x32; Q/K fragments loaded directly from global.
__global__ __launch_bounds__(64) void chunk_attn_kernel(
    const u16* __restrict__ qkv, const int* __restrict__ nchunks,
    const int* __restrict__ starts, const int* __restrict__ lens,
    u16* __restrict__ pooled) {
  __shared__ float g_lds[SEQ];
  const int h = blockIdx.x;
  const int c = blockIdx.y;
  const int b = blockIdx.z;
  const int lane = threadIdx.x;
  const int nc = min(nchunks[b], MAXC);
  u16* prow = pooled + ((size_t)(b * MAXC + c)) * DM + h * DHEAD;
  if (c >= nc) {  // empty chunk: pooled ctx = 0
    U2 z; z.x = 0; z.y = 0;
    *(U2*)(prow + lane * 2) = z;
    return;
  }
  const int s0 = starts[b * (MAXC + 1) + c];
  const int L = lens[b * MAXC + c];
  const u16* Qb = qkv + ((size_t)(b * SEQ + s0)) * QKVN + h * DHEAD;
  const u16* Kb = Qb + DM;
  const u16* Vb = Qb + 2 * DM;

  for (int j = lane; j < L; j += 64) g_lds[j] = 0.f;
  __syncthreads();

  const int col = lane & 15;   // fragment row/col index
  const int grp = lane >> 4;   // k-subgroup / row group
  const float scale = 0.08838834764831845f;  // 1/sqrt(128)
  const int NT = (L + 15) >> 4;

  for (int qt = 0; qt < NT; ++qt) {
    const int qr = qt * 16 + col;
    const int qrc = qr < L ? qr : (L - 1);  // clamp (masked later)
    bf16x8 qf[4];
#pragma unroll
    for (int s = 0; s < 4; ++s)
      qf[s] = *(const bf16x8*)(Qb + (size_t)qrc * QKVN + s * 32 + grp * 8);

    float m[4] = {-3e38f, -3e38f, -3e38f, -3e38f};
    float den[4] = {0.f, 0.f, 0.f, 0.f};
    f32x4 sc_last = {0.f, 0.f, 0.f, 0.f};

    // ---- pass 1: per-query-row online max + denom over key tiles
    for (int kt = 0; kt < NT; ++kt) {
      const int kr = kt * 16 + col;
      const bool kvalid = kr < L;
      const int krc = kvalid ? kr : (L - 1);
      f32x4 sc = {0.f, 0.f, 0.f, 0.f};
#pragma unroll
      for (int s = 0; s < 4; ++s) {
        bf16x8 kf = *(const bf16x8*)(Kb + (size_t)krc * QKVN + s * 32 + grp * 8);
        sc = __builtin_amdgcn_mfma_f32_16x16x32_bf16(qf[s], kf, sc, 0, 0, 0);
      }
      sc_last = sc;
#pragma unroll
      for (int j = 0; j < 4; ++j) {
        float sj = sc[j] * scale;
        float mv = kvalid ? sj : -3e38f;
        mv = fmaxf(mv, __shfl_xor(mv, 1));
        mv = fmaxf(mv, __shfl_xor(mv, 2));
        mv = fmaxf(mv, __shfl_xor(mv, 4));
        mv = fmaxf(mv, __shfl_xor(mv, 8));
        float mn = fmaxf(m[j], mv);
        float pv = kvalid ? __expf(sj - mn) : 0.f;
        pv += __shfl_xor(pv, 1);
        pv += __shfl_xor(pv, 2);
        pv += __shfl_xor(pv, 4);
        pv += __shfl_xor(pv, 8);
        den[j] = den[j] * __expf(m[j] - mn) + pv;
        m[j] = mn;
      }
    }
    float inv[4];
#pragma unroll
    for (int j = 0; j < 4; ++j) {
      const bool rv = (qt * 16 + grp * 4 + j) < L;
      inv[j] = rv ? 1.f / den[j] : 0.f;   // invalid rows contribute 0
    }
    // ---- pass 2: g_j += sum_rows p; NT==1 reuses pass-1 scores
    for (int kt = 0; kt < NT; ++kt) {
      const int kr = kt * 16 + col;
      const bool kvalid = kr < L;
      f32x4 sc;
      if (NT == 1) {
        sc = sc_last;
      } else {
        const int krc = kvalid ? kr : (L - 1);
        f32x4 z = {0.f, 0.f, 0.f, 0.f};
        sc = z;
#pragma unroll
        for (int s = 0; s < 4; ++s) {
          bf16x8 kf = *(const bf16x8*)(Kb + (size_t)krc * QKVN + s * 32 + grp * 8);
          sc = __builtin_amdgcn_mfma_f32_16x16x32_bf16(qf[s], kf, sc, 0, 0, 0);
        }
      }
      float colsum = 0.f;
#pragma unroll
      for (int j = 0; j < 4; ++j)
        colsum += __expf(sc[j] * scale - m[j]) * inv[j];
      colsum += __shfl_xor(colsum, 16);
      colsum += __shfl_xor(colsum, 32);
      if (grp == 0 && kvalid) g_lds[kt * 16 + col] += colsum;
    }
  }
  __syncthreads();

  // pooled = (1/L) * sum_j g_j * v_j   (lanes over dims, coalesced V)
  float a0 = 0.f, a1 = 0.f;
  for (int j = 0; j < L; ++j) {
    float gj = g_lds[j];
    U2 vv = *(const U2*)(Vb + (size_t)j * QKVN + lane * 2);
    a0 += gj * bf2f(vv.x);
    a1 += gj * bf2f(vv.y);
  }
  const float invL = 1.f / (float)L;
  U2 r; r.x = f2bf(a0 * invL); r.y = f2bf(a1 * invL);
  *(U2*)(prow + lane * 2) = r;
}

// ---------------------------------------------------------------- LayerNorm
__global__ __launch_bounds__(256) void ln_kernel(
    const float* __restrict__ h2, const float* __restrict__ gamma,
    const float* __restrict__ beta, float* __restrict__ out) {
  const int row = blockIdx.x;
  const float* x = h2 + (size_t)row * DM;
  float* o = out + (size_t)row * DM;
  const int tid = threadIdx.x;
  float v[6];
  float s = 0.f;
#pragma unroll
  for (int i = 0; i < 6; ++i) { v[i] = x[tid + i * 256]; s += v[i]; }
  __shared__ float red[8];
#pragma unroll
  for (int off = 32; off; off >>= 1) s += __shfl_xor(s, off);
  if ((tid & 63) == 0) red[tid >> 6] = s;
  __syncthreads();
  const float mu = (red[0] + red[1] + red[2] + red[3]) * (1.f / (float)DM);
  float vs = 0.f;
#pragma unroll
  for (int i = 0; i < 6; ++i) { float d = v[i] - mu; vs += d * d; }
#pragma unroll
  for (int off = 32; off; off >>= 1) vs += __shfl_xor(vs, off);
  __shared__ float red2[8];
  if ((tid & 63) == 0) red2[tid >> 6] = vs;
  __syncthreads();
  const float var = (red2[0] + red2[1] + red2[2] + red2[3]) * (1.f / (float)DM);
  const float inv = rsqrtf(var + 1e-5f);
#pragma unroll
  for (int i = 0; i < 6; ++i) {
    const int cidx = tid + i * 256;
    o[cidx] = (v[i] - mu) * inv * gamma[cidx] + beta[cidx];
  }
}

// ------------------------------------------------------------------ launch
extern "C" void kernel_launch(void* const* d_in, const int* in_sizes, int n_in,
                              void* d_out, int out_size, void* d_ws, size_t ws_size,
                              hipStream_t stream) {
  const float* x    = (const float*)d_in[0];
  const float* bnd  = (const float*)d_in[1];
  const float* wqkv = (const float*)d_in[2];
  const float* bqkv = (const float*)d_in[3];
  const float* wout = (const float*)d_in[4];
  const float* bout = (const float*)d_in[5];
  const float* w1   = (const float*)d_in[6];
  const float* b1   = (const float*)d_in[7];
  const float* w2   = (const float*)d_in[8];
  const float* b2   = (const float*)d_in[9];
  const float* lng  = (const float*)d_in[10];
  const float* lnb  = (const float*)d_in[11];
  const float* pos  = (const float*)d_in[12];
  const float* semb = (const float*)d_in[13];
  float* out = (float*)d_out;

  // workspace layout (~169 MiB)
  char* ws = (char*)d_ws;
  size_t off = 0;
  auto alloc = [&](size_t bytes) -> char* {
    char* p = ws + off;
    off += (bytes + 255) & ~(size_t)255;
    return p;
  };
  u16* x_bf    = (u16*)alloc((size_t)NB * SEQ * DM * 2);        // 25.2 MB
  u16* wqkv_bf = (u16*)alloc((size_t)3 * DM * DM * 2);          // 14.2 MB
  u16* wout_bf = (u16*)alloc((size_t)DM * DM * 2);              //  4.7 MB
  u16* w1_bf   = (u16*)alloc((size_t)2 * DM * DM * 2);          //  9.4 MB
  u16* w2_bf   = (u16*)alloc((size_t)2 * DM * DM * 2);          //  9.4 MB
  u16* qkv_bf  = (u16*)alloc((size_t)NB * SEQ * QKVN * 2);      // 75.5 MB
  int* nchunks = (int*)alloc(NB * 4);
  int* starts  = (int*)alloc(NB * (MAXC + 1) * 4);
  int* lens    = (int*)alloc(NB * MAXC * 4);
  u16* pooled  = (u16*)alloc((size_t)NB * MAXC * DM * 2);       //  6.3 MB
  u16* chunks  = (u16*)alloc((size_t)NB * MAXC * DM * 2);       //  6.3 MB
  u16* h1      = (u16*)alloc((size_t)NB * MAXC * 2 * DM * 2);   // 12.6 MB
  float* h2    = (float*)alloc((size_t)NB * MAXC * DM * 4);     // 12.6 MB
  (void)ws_size; (void)in_sizes; (void)n_in; (void)out_size;

  // f32 -> bf16 converts (single launch)
  cvt5_bf16_kernel<<<2048, 256, 0, stream>>>(
      x, x_bf, NB * SEQ * DM / 4,
      wqkv, wqkv_bf, 3 * DM * DM / 4,
      wout, wout_bf, DM * DM / 4,
      w1, w1_bf, 2 * DM * DM / 4,
      w2, w2_bf, 2 * DM * DM / 4);

  // segmentation
  segment_kernel<<<NB, 64, 0, stream>>>(bnd, nchunks, starts, lens);

  // QKV projection: [8192,1536] @ [4608,1536]^T -> bf16 [8192,4608]
  gemm_bf16_kernel<1><<<dim3(QKVN / 128, NB * SEQ / 128), 256, 0, stream>>>(
      x_bf, wqkv_bf, NB * SEQ, QKVN, DM, bqkv, qkv_bf, nullptr, nullptr, nullptr, nullptr);

  // per-chunk attention -> pooled ctx (bf16 [2048,1536])
  chunk_attn_kernel<<<dim3(NHEAD, MAXC, NB), 64, 0, stream>>>(
      qkv_bf, nchunks, starts, lens, pooled);

  // out-proj + chunk assembly: [2048,1536] @ [1536,1536]^T -> chunks bf16
  gemm_bf16_kernel<2><<<dim3(DM / 128, NB * MAXC / 128), 256, 0, stream>>>(
      pooled, wout_bf, NB * MAXC, DM, DM, bout, chunks, nullptr, lens, semb, pos);

  // MLP fc1 + GELU: [2048,1536] @ [3072,1536]^T -> h1 bf16
  gemm_bf16_kernel<3><<<dim3(2 * DM / 128, NB * MAXC / 128), 256, 0, stream>>>(
      chunks, w1_bf, NB * MAXC, 2 * DM, DM, b1, h1, nullptr, nullptr, nullptr, nullptr);

  // MLP fc2: [2048,3072] @ [1536,3072]^T -> h2 f32
  gemm_bf16_kernel<4><<<dim3(DM / 128, NB * MAXC / 128), 256, 0, stream>>>(
      h1, w2_bf, NB * MAXC, DM, 2 * DM, b2, nullptr, h2, nullptr, nullptr, nullptr);

  // LayerNorm -> d_out
  ln_kernel<<<NB * MAXC, 256, 0, stream>>>(h2, lng, lnb, out);
}

// Round 5
// 404.589 us; speedup vs baseline: 1.2678x; 1.0057x over previous
//
#include <hip/hip_runtime.h>
#include <math.h>

// Problem constants
#define NB 8
#define SEQ 1024
#define DM 1536
#define NHEAD 12
#define DHEAD 128
#define MAXC 256
#define QKVN 4608
#define THRESH 0.85f

typedef unsigned short u16;
typedef __attribute__((ext_vector_type(8))) __bf16 bf16x8;
typedef __attribute__((ext_vector_type(4))) float f32x4;

struct __align__(4) U2 { u16 x, y; };
struct __align__(8) U4 { u16 x, y, z, w; };

__device__ __forceinline__ float bf2f(u16 u) {
  union { unsigned i; float f; } c; c.i = ((unsigned)u) << 16; return c.f;
}
__device__ __forceinline__ u16 f2bf(float f) {
  union { float f; unsigned i; } c; c.f = f;
  unsigned r = c.i + 0x7FFFu + ((c.i >> 16) & 1u);  // RNE
  return (u16)(r >> 16);
}

// ---------------------------------------------------------------- converts
__global__ __launch_bounds__(256) void cvt5_bf16_kernel(
    const float* __restrict__ i0, u16* __restrict__ o0, int n0,
    const float* __restrict__ i1, u16* __restrict__ o1, int n1,
    const float* __restrict__ i2, u16* __restrict__ o2, int n2,
    const float* __restrict__ i3, u16* __restrict__ o3, int n3,
    const float* __restrict__ i4, u16* __restrict__ o4, int n4) {
  const int stride = gridDim.x * blockDim.x;
  const int t0 = blockIdx.x * blockDim.x + threadIdx.x;
  const float* ins[5] = {i0, i1, i2, i3, i4};
  u16* outs[5] = {o0, o1, o2, o3, o4};
  const int ns[5] = {n0, n1, n2, n3, n4};
#pragma unroll
  for (int a = 0; a < 5; ++a) {
    const float* in = ins[a];
    u16* out = outs[a];
    for (int i = t0; i < ns[a]; i += stride) {
      float4 f = ((const float4*)in)[i];
      U4 u; u.x = f2bf(f.x); u.y = f2bf(f.y); u.z = f2bf(f.z); u.w = f2bf(f.w);
      ((U4*)out)[i] = u;
    }
  }
}

// ------------------------------------------------------------- segmentation
__global__ __launch_bounds__(64) void segment_kernel(
    const float* __restrict__ bnd, int* __restrict__ nchunks,
    int* __restrict__ starts, int* __restrict__ lens) {
  const int b = blockIdx.x;
  const int lane = threadIdx.x;
  int running = 0;
  for (int g = 0; g < SEQ / 64; ++g) {
    int s = g * 64 + lane;
    bool isb = bnd[b * SEQ + s] > THRESH;
    unsigned long long mask = __ballot(isb ? 1 : 0);
    int excl = __popcll(mask & ((1ULL << lane) - 1ULL));
    if (isb) {
      int c = running + excl;
      if (c <= MAXC) starts[b * (MAXC + 1) + c] = s;
    }
    running += __popcll(mask);
  }
  if (lane == 0) nchunks[b] = running;
  __syncthreads();
  int ncl = min(running, MAXC);
  for (int c = lane; c < MAXC; c += 64) {
    int v = 0;
    if (c < ncl) {
      int st = starts[b * (MAXC + 1) + c];
      int en = (c + 1 < running) ? starts[b * (MAXC + 1) + c + 1] : SEQ;
      v = en - st;
    }
    lens[b * MAXC + c] = v;
  }
}

// --------------------------------------------------- 256x256 pipelined GEMM
// C[M,N] = A[M,K] @ B[N,K]^T + bias, bf16 in, bf16 out. M,N multiples of 256.
// 512 threads = 8 waves (2 Mx4 N), per-wave 128x64 output (8x4 16x16 frags).
// BK=32; 3 LDS buffers (96KB); prefetch distance 2; counted vmcnt(4) per
// K-tile (never 0 in steady state). Per K-tile: 2 phases x 16 MFMA, each
// {ds_read || 2x global_load_lds -> barrier -> lgkmcnt(0)+sched_barrier ->
//  setprio(1) MFMA setprio(0) -> barrier}.
// LDS chunk involution sigma(c)=c^((c>>3)&7) per 16-row group (64 chunks of
// 16B): staging source permuted within 128B row-pairs (coalescing intact),
// fragment ds_read 2 lanes/bank-group => conflict-free (verified round 4).
__global__ __launch_bounds__(512, 2) void gemm256_kernel(
    const u16* __restrict__ A, const u16* __restrict__ B,
    const int M, const int N, const int K,
    const float* __restrict__ bias, u16* __restrict__ outB) {
  __shared__ __align__(16) u16 lds[3][2][8192];  // [buf][A/B][1024 slots * 8]
  const int tid = threadIdx.x;
  const int wid = tid >> 6;
  const int lane = tid & 63;
  // XCD-aware bijective swizzle (gridDim.x % 8 == 0)
  const int cpx = gridDim.x >> 3;
  const int bid = ((int)blockIdx.x & 7) * cpx + ((int)blockIdx.x >> 3);
  const int NX = N >> 8;
  const int row0 = (bid / NX) << 8;
  const int col0 = (bid % NX) << 8;

  const int wr = wid >> 2;   // 0..1  (M half)
  const int wc = wid & 3;    // 0..3  (N quarter)
  const int rr = lane & 15;
  const int kg = lane >> 4;  // 0..3
  // fragment-read slot within a 16-row group
  const int cw = rr * 4 + kg;
  const int slot = cw ^ ((cw >> 3) & 7);
  // staging decomposition: call i, slot s = i*512 + tid
  int srow[2], sk8[2];
#pragma unroll
  for (int i = 0; i < 2; ++i) {
    const int s = i * 512 + tid;
    const int g = s >> 6, c = s & 63;
    const int gch = c ^ ((c >> 3) & 7);
    srow[i] = g * 16 + (gch >> 2);
    sk8[i] = gch & 3;
  }

  const int NT = K >> 5;  // K-tiles of 32

#define STAGE_A(t)                                                            \
  {                                                                           \
    const int _b = (t) % 3;                                                   \
    const int _kb = (t) << 5;                                                 \
    _Pragma("unroll") for (int i = 0; i < 2; ++i) {                           \
      u16* ga = const_cast<u16*>(A) + (size_t)(row0 + srow[i]) * K + _kb +    \
                sk8[i] * 8;                                                   \
      __builtin_amdgcn_global_load_lds(                                       \
          (__attribute__((address_space(1))) void*)ga,                        \
          (__attribute__((address_space(3))) void*)&lds[_b][0]                \
              [(i * 512 + wid * 64) * 8], 16, 0, 0);                          \
    }                                                                         \
  }
#define STAGE_B(t)                                                            \
  {                                                                           \
    const int _b = (t) % 3;                                                   \
    const int _kb = (t) << 5;                                                 \
    _Pragma("unroll") for (int i = 0; i < 2; ++i) {                           \
      u16* gb = const_cast<u16*>(B) + (size_t)(col0 + srow[i]) * K + _kb +    \
                sk8[i] * 8;                                                   \
      __builtin_amdgcn_global_load_lds(                                       \
          (__attribute__((address_space(1))) void*)gb,                        \
          (__attribute__((address_space(3))) void*)&lds[_b][1]                \
              [(i * 512 + wid * 64) * 8], 16, 0, 0);                          \
    }                                                                         \
  }

  f32x4 acc[8][4] = {};

  // prologue: tiles 0 and 1 in flight; wait tile 0 resident
  STAGE_A(0); STAGE_B(0);
  STAGE_A(1); STAGE_B(1);
  asm volatile("s_waitcnt vmcnt(4)" ::: "memory");
  __builtin_amdgcn_s_barrier();

  for (int t = 0; t < NT; ++t) {
    const int buf = t % 3;
    // ---------------- phase 0: m 0..3 x n 0..3
    bf16x8 a0[4], b0[4];
#pragma unroll
    for (int m = 0; m < 4; ++m)
      a0[m] = *(const bf16x8*)&lds[buf][0][((wr * 8 + m) * 64 + slot) * 8];
#pragma unroll
    for (int n = 0; n < 4; ++n)
      b0[n] = *(const bf16x8*)&lds[buf][1][((wc * 4 + n) * 64 + slot) * 8];
    if (t + 2 < NT) STAGE_A(t + 2);
    __builtin_amdgcn_s_barrier();
    asm volatile("s_waitcnt lgkmcnt(0)" ::: "memory");
    __builtin_amdgcn_sched_barrier(0);
    __builtin_amdgcn_s_setprio(1);
#pragma unroll
    for (int m = 0; m < 4; ++m)
#pragma unroll
      for (int n = 0; n < 4; ++n)
        acc[m][n] = __builtin_amdgcn_mfma_f32_16x16x32_bf16(a0[m], b0[n], acc[m][n], 0, 0, 0);
    __builtin_amdgcn_s_setprio(0);
    __builtin_amdgcn_s_barrier();
    // ---------------- phase 1: m 4..7 x n 0..3 (B reused in registers)
    bf16x8 a1[4];
#pragma unroll
    for (int m = 0; m < 4; ++m)
      a1[m] = *(const bf16x8*)&lds[buf][0][((wr * 8 + 4 + m) * 64 + slot) * 8];
    if (t + 2 < NT) {
      STAGE_B(t + 2);
      asm volatile("s_waitcnt vmcnt(4)" ::: "memory");  // t+1 resident
    } else if (t + 1 < NT) {
      asm volatile("s_waitcnt vmcnt(0)" ::: "memory");  // drain for last tile
    }
    __builtin_amdgcn_s_barrier();
    asm volatile("s_waitcnt lgkmcnt(0)" ::: "memory");
    __builtin_amdgcn_sched_barrier(0);
    __builtin_amdgcn_s_setprio(1);
#pragma unroll
    for (int m = 0; m < 4; ++m)
#pragma unroll
      for (int n = 0; n < 4; ++n)
        acc[4 + m][n] = __builtin_amdgcn_mfma_f32_16x16x32_bf16(a1[m], b0[n], acc[4 + m][n], 0, 0, 0);
    __builtin_amdgcn_s_setprio(0);
    __builtin_amdgcn_s_barrier();
  }
#undef STAGE_A
#undef STAGE_B

  // epilogue: C/D layout col = lane&15, row = (lane>>4)*4 + reg
#pragma unroll
  for (int m = 0; m < 8; ++m) {
#pragma unroll
    for (int n = 0; n < 4; ++n) {
      const int col = col0 + wc * 64 + n * 16 + rr;
      const float bs = bias[col];
#pragma unroll
      for (int j = 0; j < 4; ++j) {
        const int row = row0 + wr * 128 + m * 16 + (lane >> 4) * 4 + j;
        outB[(size_t)row * N + col] = f2bf(acc[m][n][j] + bs);
      }
    }
  }
}

// -------------------------------------------------------------- 128^2 GEMM
// (round-4 structure, sigma-swizzled LDS, 0 conflicts) for the small GEMMs.
// MODE 2: chunks epilogue (zero-if-empty, +out_b +size_emb +pos_enc) -> bf16
// MODE 3: out_bf16 = gelu(acc + bias)                    (MLP fc1)
// MODE 4: out_f32  = acc + bias                          (MLP fc2)
template <int MODE>
__global__ __launch_bounds__(256) void gemm_bf16_kernel(
    const u16* __restrict__ A, const u16* __restrict__ B,
    const int M, const int N, const int K,
    const float* __restrict__ bias,
    u16* __restrict__ outB, float* __restrict__ outF,
    const int* __restrict__ lens, const float* __restrict__ semb,
    const float* __restrict__ pos) {
  __shared__ __align__(16) u16 As[128 * 32];
  __shared__ __align__(16) u16 Bs[128 * 32];
  const int tid = threadIdx.x;
  const int wave = tid >> 6;
  const int lane = tid & 63;
  const int row0 = blockIdx.y * 128;
  const int col0 = blockIdx.x * 128;
  const int wm = (wave >> 1) * 64;
  const int wn = (wave & 1) * 64;
  const int gch = lane ^ ((lane >> 3) & 7);
  const int sr = gch >> 2;
  const int sc = (gch & 3) * 8;
  const int rr = lane & 15;
  const int kg = lane >> 4;
  const int cwant = rr * 4 + kg;
  const int slot = cwant ^ ((cwant >> 3) & 7);
  f32x4 acc[4][4] = {};

  for (int k0 = 0; k0 < K; k0 += 32) {
    __syncthreads();
#pragma unroll
    for (int t = 0; t < 2; ++t) {
      const int li = wave * 2 + t;
      u16* ga = const_cast<u16*>(A) + (size_t)(row0 + li * 16 + sr) * K + (k0 + sc);
      u16* gb = const_cast<u16*>(B) + (size_t)(col0 + li * 16 + sr) * K + (k0 + sc);
      __builtin_amdgcn_global_load_lds(
          (__attribute__((address_space(1))) void*)ga,
          (__attribute__((address_space(3))) void*)(As + li * 512), 16, 0, 0);
      __builtin_amdgcn_global_load_lds(
          (__attribute__((address_space(1))) void*)gb,
          (__attribute__((address_space(3))) void*)(Bs + li * 512), 16, 0, 0);
    }
    __syncthreads();
    bf16x8 af[4], bfr[4];
#pragma unroll
    for (int m = 0; m < 4; ++m)
      af[m] = *(const bf16x8*)(As + ((wm >> 4) + m) * 512 + slot * 8);
#pragma unroll
    for (int n = 0; n < 4; ++n)
      bfr[n] = *(const bf16x8*)(Bs + ((wn >> 4) + n) * 512 + slot * 8);
#pragma unroll
    for (int m = 0; m < 4; ++m)
#pragma unroll
      for (int n = 0; n < 4; ++n)
        acc[m][n] = __builtin_amdgcn_mfma_f32_16x16x32_bf16(af[m], bfr[n], acc[m][n], 0, 0, 0);
  }

  const int rg = (lane >> 4) * 4;
#pragma unroll
  for (int m = 0; m < 4; ++m) {
#pragma unroll
    for (int n = 0; n < 4; ++n) {
      const int col = col0 + wn + n * 16 + rr;
#pragma unroll
      for (int j = 0; j < 4; ++j) {
        const int row = row0 + wm + m * 16 + rg + j;
        float v = acc[m][n][j];
        if (MODE == 2) {
          const int len = lens[row];
          float val = 0.f;
          if (len > 0) {
            const int si = len < 1023 ? len : 1023;
            val = v + bias[col] + semb[(size_t)si * DM + col];
          }
          val += pos[(size_t)(row & (MAXC - 1)) * DM + col];
          outB[(size_t)row * N + col] = f2bf(val);
        } else if (MODE == 3) {
          float z = v + bias[col];
          float gel = 0.5f * z * (1.f + erff(z * 0.70710678118654752440f));
          outB[(size_t)row * N + col] = f2bf(gel);
        } else {
          outF[(size_t)row * N + col] = v + bias[col];
        }
      }
    }
  }
}

// -------------------------------------------------------- chunk attention
__global__ __launch_bounds__(64) void chunk_attn_kernel(
    const u16* __restrict__ qkv, const int* __restrict__ nchunks,
    const int* __restrict__ starts, const int* __restrict__ lens,
    u16* __restrict__ pooled) {
  __shared__ float g_lds[SEQ];
  const int h = blockIdx.x;
  const int c = blockIdx.y;
  const int b = blockIdx.z;
  const int lane = threadIdx.x;
  const int nc = min(nchunks[b], MAXC);
  u16* prow = pooled + ((size_t)(b * MAXC + c)) * DM + h * DHEAD;
  if (c >= nc) {
    U2 z; z.x = 0; z.y = 0;
    *(U2*)(prow + lane * 2) = z;
    return;
  }
  const int s0 = starts[b * (MAXC + 1) + c];
  const int L = lens[b * MAXC + c];
  const u16* Qb = qkv + ((size_t)(b * SEQ + s0)) * QKVN + h * DHEAD;
  const u16* Kb = Qb + DM;
  const u16* Vb = Qb + 2 * DM;

  for (int j = lane; j < L; j += 64) g_lds[j] = 0.f;
  __syncthreads();

  const int col = lane & 15;
  const int grp = lane >> 4;
  const float scale = 0.08838834764831845f;
  const int NT = (L + 15) >> 4;

  for (int qt = 0; qt < NT; ++qt) {
    const int qr = qt * 16 + col;
    const int qrc = qr < L ? qr : (L - 1);
    bf16x8 qf[4];
#pragma unroll
    for (int s = 0; s < 4; ++s)
      qf[s] = *(const bf16x8*)(Qb + (size_t)qrc * QKVN + s * 32 + grp * 8);

    float m[4] = {-3e38f, -3e38f, -3e38f, -3e38f};
    float den[4] = {0.f, 0.f, 0.f, 0.f};
    f32x4 sc_last = {0.f, 0.f, 0.f, 0.f};

    for (int kt = 0; kt < NT; ++kt) {
      const int kr = kt * 16 + col;
      const bool kvalid = kr < L;
      const int krc = kvalid ? kr : (L - 1);
      f32x4 sc = {0.f, 0.f, 0.f, 0.f};
#pragma unroll
      for (int s = 0; s < 4; ++s) {
        bf16x8 kf = *(const bf16x8*)(Kb + (size_t)krc * QKVN + s * 32 + grp * 8);
        sc = __builtin_amdgcn_mfma_f32_16x16x32_bf16(qf[s], kf, sc, 0, 0, 0);
      }
      sc_last = sc;
#pragma unroll
      for (int j = 0; j < 4; ++j) {
        float sj = sc[j] * scale;
        float mv = kvalid ? sj : -3e38f;
        mv = fmaxf(mv, __shfl_xor(mv, 1));
        mv = fmaxf(mv, __shfl_xor(mv, 2));
        mv = fmaxf(mv, __shfl_xor(mv, 4));
        mv = fmaxf(mv, __shfl_xor(mv, 8));
        float mn = fmaxf(m[j], mv);
        float pv = kvalid ? __expf(sj - mn) : 0.f;
        pv += __shfl_xor(pv, 1);
        pv += __shfl_xor(pv, 2);
        pv += __shfl_xor(pv, 4);
        pv += __shfl_xor(pv, 8);
        den[j] = den[j] * __expf(m[j] - mn) + pv;
        m[j] = mn;
      }
    }
    float inv[4];
#pragma unroll
    for (int j = 0; j < 4; ++j) {
      const bool rv = (qt * 16 + grp * 4 + j) < L;
      inv[j] = rv ? 1.f / den[j] : 0.f;
    }
    for (int kt = 0; kt < NT; ++kt) {
      const int kr = kt * 16 + col;
      const bool kvalid = kr < L;
      f32x4 sc;
      if (NT == 1) {
        sc = sc_last;
      } else {
        const int krc = kvalid ? kr : (L - 1);
        f32x4 z = {0.f, 0.f, 0.f, 0.f};
        sc = z;
#pragma unroll
        for (int s = 0; s < 4; ++s) {
          bf16x8 kf = *(const bf16x8*)(Kb + (size_t)krc * QKVN + s * 32 + grp * 8);
          sc = __builtin_amdgcn_mfma_f32_16x16x32_bf16(qf[s], kf, sc, 0, 0, 0);
        }
      }
      float colsum = 0.f;
#pragma unroll
      for (int j = 0; j < 4; ++j)
        colsum += __expf(sc[j] * scale - m[j]) * inv[j];
      colsum += __shfl_xor(colsum, 16);
      colsum += __shfl_xor(colsum, 32);
      if (grp == 0 && kvalid) g_lds[kt * 16 + col] += colsum;
    }
  }
  __syncthreads();

  float a0 = 0.f, a1 = 0.f;
  for (int j = 0; j < L; ++j) {
    float gj = g_lds[j];
    U2 vv = *(const U2*)(Vb + (size_t)j * QKVN + lane * 2);
    a0 += gj * bf2f(vv.x);
    a1 += gj * bf2f(vv.y);
  }
  const float invL = 1.f / (float)L;
  U2 r; r.x = f2bf(a0 * invL); r.y = f2bf(a1 * invL);
  *(U2*)(prow + lane * 2) = r;
}

// ---------------------------------------------------------------- LayerNorm
__global__ __launch_bounds__(256) void ln_kernel(
    const float* __restrict__ h2, const float* __restrict__ gamma,
    const float* __restrict__ beta, float* __restrict__ out) {
  const int row = blockIdx.x;
  const float* x = h2 + (size_t)row * DM;
  float* o = out + (size_t)row * DM;
  const int tid = threadIdx.x;
  float v[6];
  float s = 0.f;
#pragma unroll
  for (int i = 0; i < 6; ++i) { v[i] = x[tid + i * 256]; s += v[i]; }
  __shared__ float red[8];
#pragma unroll
  for (int off = 32; off; off >>= 1) s += __shfl_xor(s, off);
  if ((tid & 63) == 0) red[tid >> 6] = s;
  __syncthreads();
  const float mu = (red[0] + red[1] + red[2] + red[3]) * (1.f / (float)DM);
  float vs = 0.f;
#pragma unroll
  for (int i = 0; i < 6; ++i) { float d = v[i] - mu; vs += d * d; }
#pragma unroll
  for (int off = 32; off; off >>= 1) vs += __shfl_xor(vs, off);
  __shared__ float red2[8];
  if ((tid & 63) == 0) red2[tid >> 6] = vs;
  __syncthreads();
  const float var = (red2[0] + red2[1] + red2[2] + red2[3]) * (1.f / (float)DM);
  const float inv = rsqrtf(var + 1e-5f);
#pragma unroll
  for (int i = 0; i < 6; ++i) {
    const int cidx = tid + i * 256;
    o[cidx] = (v[i] - mu) * inv * gamma[cidx] + beta[cidx];
  }
}

// ------------------------------------------------------------------ launch
extern "C" void kernel_launch(void* const* d_in, const int* in_sizes, int n_in,
                              void* d_out, int out_size, void* d_ws, size_t ws_size,
                              hipStream_t stream) {
  const float* x    = (const float*)d_in[0];
  const float* bnd  = (const float*)d_in[1];
  const float* wqkv = (const float*)d_in[2];
  const float* bqkv = (const float*)d_in[3];
  const float* wout = (const float*)d_in[4];
  const float* bout = (const float*)d_in[5];
  const float* w1   = (const float*)d_in[6];
  const float* b1   = (const float*)d_in[7];
  const float* w2   = (const float*)d_in[8];
  const float* b2   = (const float*)d_in[9];
  const float* lng  = (const float*)d_in[10];
  const float* lnb  = (const float*)d_in[11];
  const float* pos  = (const float*)d_in[12];
  const float* semb = (const float*)d_in[13];
  float* out = (float*)d_out;

  char* ws = (char*)d_ws;
  size_t off = 0;
  auto alloc = [&](size_t bytes) -> char* {
    char* p = ws + off;
    off += (bytes + 255) & ~(size_t)255;
    return p;
  };
  u16* x_bf    = (u16*)alloc((size_t)NB * SEQ * DM * 2);
  u16* wqkv_bf = (u16*)alloc((size_t)3 * DM * DM * 2);
  u16* wout_bf = (u16*)alloc((size_t)DM * DM * 2);
  u16* w1_bf   = (u16*)alloc((size_t)2 * DM * DM * 2);
  u16* w2_bf   = (u16*)alloc((size_t)2 * DM * DM * 2);
  u16* qkv_bf  = (u16*)alloc((size_t)NB * SEQ * QKVN * 2);
  int* nchunks = (int*)alloc(NB * 4);
  int* starts  = (int*)alloc(NB * (MAXC + 1) * 4);
  int* lens    = (int*)alloc(NB * MAXC * 4);
  u16* pooled  = (u16*)alloc((size_t)NB * MAXC * DM * 2);
  u16* chunks  = (u16*)alloc((size_t)NB * MAXC * DM * 2);
  u16* h1      = (u16*)alloc((size_t)NB * MAXC * 2 * DM * 2);
  float* h2    = (float*)alloc((size_t)NB * MAXC * DM * 4);
  (void)ws_size; (void)in_sizes; (void)n_in; (void)out_size;

  cvt5_bf16_kernel<<<2048, 256, 0, stream>>>(
      x, x_bf, NB * SEQ * DM / 4,
      wqkv, wqkv_bf, 3 * DM * DM / 4,
      wout, wout_bf, DM * DM / 4,
      w1, w1_bf, 2 * DM * DM / 4,
      w2, w2_bf, 2 * DM * DM / 4);

  segment_kernel<<<NB, 64, 0, stream>>>(bnd, nchunks, starts, lens);

  // QKV projection: [8192,1536] @ [4608,1536]^T -> bf16, 256^2 pipelined
  gemm256_kernel<<<(NB * SEQ / 256) * (QKVN / 256), 512, 0, stream>>>(
      x_bf, wqkv_bf, NB * SEQ, QKVN, DM, bqkv, qkv_bf);

  chunk_attn_kernel<<<dim3(NHEAD, MAXC, NB), 64, 0, stream>>>(
      qkv_bf, nchunks, starts, lens, pooled);

  gemm_bf16_kernel<2><<<dim3(DM / 128, NB * MAXC / 128), 256, 0, stream>>>(
      pooled, wout_bf, NB * MAXC, DM, DM, bout, chunks, nullptr, lens, semb, pos);

  gemm_bf16_kernel<3><<<dim3(2 * DM / 128, NB * MAXC / 128), 256, 0, stream>>>(
      chunks, w1_bf, NB * MAXC, 2 * DM, DM, b1, h1, nullptr, nullptr, nullptr, nullptr);

  gemm_bf16_kernel<4><<<dim3(DM / 128, NB * MAXC / 128), 256, 0, stream>>>(
      h1, w2_bf, NB * MAXC, DM, 2 * DM, b2, nullptr, h2, nullptr, nullptr, nullptr);

  ln_kernel<<<NB * MAXC, 256, 0, stream>>>(h2, lng, lnb, out);
}